// Round 1
// baseline (2853.341 us; speedup 1.0000x reference)
//
#include <hip/hip_runtime.h>
#include <math.h>

// ---------------------------------------------------------------------------
// TDS decoder R5: 64 persistent blocks x 1024 threads, tag-fused sync.
//  - Single-writer decide regions: each block stores {value,tag} as one 8B
//    atomic. Readers poll data directly (tag==t) -> detect+gather fused into
//    ONE MALL round. No counters, no atomicAdd RMW, no zero pass, no go_lds.
//  - GRU gh rows are tagged the same way: GRU waves poll gh directly and
//    overlap with wave0's decide.
//  - 128 K rows/block in registers (8/wave); W_hh aux rows + W_out hp row in
//    LDS; M columns in registers. 2 alternating buffers, tags disambiguate.
// ---------------------------------------------------------------------------

#define NV      40
#define TENC    8192
#define MAXLEN  200
#define EOS_IDX 38
#define NB      64
#define NT      1024
#define NW      16
#define ROWS    128                   /* enc rows per block                 */
#define RPW     8                     /* enc rows per wave                  */
#define GHROWS  24                    /* W_hh rows per block (1536/64)      */
#define RSTRIDE 96                    /* floats per decide region (48x8B)   */
#define SCALE   0.04419417382415922f  /* 1/sqrt(512) */

/* ws layout (floats) */
#define WS_READY 0                            /* 64 x 8B                     */
#define WS_DEC   128                          /* 2 buf x 64 reg x 96        */
#define WS_HP    (WS_DEC + 2 * NB * RSTRIDE)  /* 12416: 2 x 96              */
#define WS_GH    (WS_HP + 2 * RSTRIDE)        /* 12608: 2 x 1536 x 2        */
#define WS_GI    (WS_GH + 2 * 3072)           /* 18752: 40 x 1536           */

typedef unsigned long long u64;

__device__ __forceinline__ void st_tag(float* p, float v, int tag) {
  const u64 x = ((u64)(unsigned)tag << 32) | (u64)__float_as_uint(v);
  __hip_atomic_store((u64*)p, x, __ATOMIC_RELAXED, __HIP_MEMORY_SCOPE_AGENT);
}
__device__ __forceinline__ void st_tag_rel(float* p, float v, int tag) {
  const u64 x = ((u64)(unsigned)tag << 32) | (u64)__float_as_uint(v);
  __hip_atomic_store((u64*)p, x, __ATOMIC_RELEASE, __HIP_MEMORY_SCOPE_AGENT);
}
__device__ __forceinline__ u64 ld_tag(float* p) {
  return __hip_atomic_load((u64*)p, __ATOMIC_RELAXED, __HIP_MEMORY_SCOPE_AGENT);
}
#define TAGOF(x) ((int)(unsigned)((x) >> 32))
#define VALOF(x) __uint_as_float((unsigned)(x))

__device__ __forceinline__ int ld_lds_acq(int* p) {
  return __hip_atomic_load(p, __ATOMIC_ACQUIRE, __HIP_MEMORY_SCOPE_WORKGROUP);
}
__device__ __forceinline__ void st_lds_rel(int* p, int v) {
  __hip_atomic_store(p, v, __ATOMIC_RELEASE, __HIP_MEMORY_SCOPE_WORKGROUP);
}

__device__ __forceinline__ float wred(float s) {
#pragma unroll
  for (int o = 32; o > 0; o >>= 1) s += __shfl_xor(s, o, 64);
  return s;
}
__device__ __forceinline__ float dot8(float4 a0, float4 a1, float4 b0,
                                      float4 b1) {
  return a0.x * b0.x + a0.y * b0.y + a0.z * b0.z + a0.w * b0.w +
         a1.x * b1.x + a1.y * b1.y + a1.z * b1.z + a1.w * b1.w;
}
__device__ __forceinline__ float wdot512(const float* __restrict__ a,
                                         const float* __restrict__ b) {
  const int l = threadIdx.x & 63;
  const float4 a0 = ((const float4*)a)[l];
  const float4 a1 = ((const float4*)a)[l + 64];
  const float4 b0 = ((const float4*)b)[l];
  const float4 b1 = ((const float4*)b)[l + 64];
  return wred(dot8(a0, a1, b0, b1));
}

__global__ void dec_init(int* wsi) {
  for (int k = threadIdx.x; k < WS_GI; k += NT) wsi[k] = 0;
}

__global__ void __launch_bounds__(NT, 4) dec_main(
    const float* __restrict__ enc, const float* __restrict__ hidden,
    const float* __restrict__ embed, const float* __restrict__ w_ih,
    const float* __restrict__ w_hh, const float* __restrict__ b_ih,
    const float* __restrict__ b_hh, const float* __restrict__ w_out,
    const float* __restrict__ b_out, float* __restrict__ o,
    float* __restrict__ ws) {
  const int b = blockIdx.x, tid = threadIdx.x;
  const int wave = tid >> 6, lane = tid & 63;
  const int r0 = b * ROWS;

  __shared__ __align__(16) float h_lds[512];
  __shared__ __align__(16) float whh_lds[GHROWS * 512];  /* 48 KB */
  __shared__ __align__(16) float whp_lds[512];
  __shared__ float pw_lds[NW * 48];
  __shared__ float sc_lds[1];
  __shared__ int bf_lds;  /* (t<<6)|best */

  // ----------------- prologue: LDS staging -----------------
  if (tid < 512) h_lds[tid] = hidden[tid];
  {
    const float4* src = (const float4*)(w_hh + (size_t)b * GHROWS * 512);
    float4* dst = (float4*)whh_lds;
#pragma unroll
    for (int i = 0; i < 3; ++i) dst[tid + i * NT] = src[tid + i * NT];
  }
  if (b < NV && tid < 128)
    ((float4*)whp_lds)[tid] =
        ((const float4*)(w_out + (size_t)b * 1024 + 512))[tid];
  if (tid == 0) bf_lds = -1;
  __syncthreads();

  // gi_all[v][j] = W_ih[j].embed[v] + b_ih[j]   (960 dots per block)
  for (int u = wave; u < 960; u += NW) {
    const int gl = b * 960 + u;
    const int v = gl / 1536, j = gl - v * 1536;
    const float d = wdot512(w_ih + (size_t)j * 512, embed + (size_t)v * 512);
    if (lane == 0) ws[WS_GI + (size_t)v * 1536 + j] = d + b_ih[j];
  }

  // M columns: Mv[r][lane] = W_out[lane,:512].V[row r]; lane40 = 1 (S col)
  const float* rowp = enc + (size_t)(r0 + wave * RPW) * 1024;
  float Mv[RPW];
#pragma unroll
  for (int r = 0; r < RPW; ++r) Mv[r] = (lane == 40) ? 1.0f : 0.0f;
  {
    float4 va[RPW], vb[RPW];
#pragma unroll
    for (int r = 0; r < RPW; ++r) {
      va[r] = ((const float4*)(rowp + r * 1024 + 512))[lane];
      vb[r] = ((const float4*)(rowp + r * 1024 + 512))[lane + 64];
    }
    for (int v = 0; v < NV; ++v) {
      const float* wp = w_out + (size_t)v * 1024;
      const float4 w0 = ((const float4*)wp)[lane];
      const float4 w1 = ((const float4*)wp)[lane + 64];
#pragma unroll
      for (int r = 0; r < RPW; ++r) {
        const float s = wred(dot8(va[r], vb[r], w0, w1));
        if (lane == v) Mv[r] = s;
      }
    }
  }
  // K rows into registers (re-uses the va/vb register budget)
  float4 ka[RPW], kb[RPW];
#pragma unroll
  for (int r = 0; r < RPW; ++r) {
    ka[r] = ((const float4*)(rowp + r * 1024))[lane];
    kb[r] = ((const float4*)(rowp + r * 1024))[lane + 64];
  }

  // biases + gh(h0) -> buffer 1, tag 1
  float ghbias0 = 0.f, ghbias1 = 0.f, hpbias = 0.f;
  if (b < NV) hpbias = b_out[b];
  if (wave >= 1 && wave <= 12) {
    const int jr = (wave - 1) * 2;
    ghbias0 = b_hh[b * GHROWS + jr];
    ghbias1 = b_hh[b * GHROWS + jr + 1];
    const float4 hh0 = ((const float4*)h_lds)[lane];
    const float4 hh1 = ((const float4*)h_lds)[lane + 64];
    const float d0 = wred(dot8(((const float4*)(whh_lds + jr * 512))[lane],
                               ((const float4*)(whh_lds + jr * 512))[lane + 64],
                               hh0, hh1));
    const float d1 =
        wred(dot8(((const float4*)(whh_lds + (jr + 1) * 512))[lane],
                  ((const float4*)(whh_lds + (jr + 1) * 512))[lane + 64], hh0,
                  hh1));
    if (lane == 0) {
      st_tag(&ws[WS_GH + 3072 + 2 * (b * GHROWS + jr)], d0 + ghbias0, 1);
      st_tag(&ws[WS_GH + 3072 + 2 * (b * GHROWS + jr + 1)], d1 + ghbias1, 1);
    }
  }
  __syncthreads();  /* drain (vmcnt0) all prologue stores */
  if (tid == 0) st_tag_rel(&ws[WS_READY + 2 * b], 0.f, 1);  /* wbL2 + marker */

  // ----------------- main loop -----------------
  int eos_reg = -1;            /* block0/wave0/lane0 only */
  float pz[RPW];               /* this wave's unnormalized attention weights */
#pragma unroll
  for (int r = 0; r < RPW; ++r) pz[r] = 0.f;
  float* attn = o + (size_t)MAXLEN * NV + 1;

  for (int t = 0; t <= MAXLEN; ++t) {
    if (wave == 0) {
      if (t == 0) {
        bool ok = (lane >= NB);
        for (;;) {
          if (!ok) ok = (TAGOF(ld_tag(&ws[WS_READY + 2 * lane])) == 1);
          if (__ballot(!ok) == 0ull) break;
          __builtin_amdgcn_s_sleep(1);
        }
        if (lane == 0) st_lds_rel(&bf_lds, EOS_IDX);  /* (0<<6)|EOS */
      } else {
        // ---- fused poll+gather: data carries its own tag ----
        float* dbuf = ws + WS_DEC + (size_t)(t & 1) * (NB * RSTRIDE);
        float* hpb = ws + WS_HP + (size_t)(t & 1) * RSTRIDE;
        float cs = 0.f, hp = 0.f;
        for (;;) {
          int ok = 1;
          float c0 = 0, c1 = 0, c2 = 0, c3 = 0, hv = 0;
          if (lane < 41) {
#pragma unroll 4
            for (int q = 0; q < NB / 4; ++q) {
              const u64 a0 = ld_tag(&dbuf[(4 * q + 0) * RSTRIDE + 2 * lane]);
              const u64 a1 = ld_tag(&dbuf[(4 * q + 1) * RSTRIDE + 2 * lane]);
              const u64 a2 = ld_tag(&dbuf[(4 * q + 2) * RSTRIDE + 2 * lane]);
              const u64 a3 = ld_tag(&dbuf[(4 * q + 3) * RSTRIDE + 2 * lane]);
              c0 += VALOF(a0); c1 += VALOF(a1);
              c2 += VALOF(a2); c3 += VALOF(a3);
              ok &= (TAGOF(a0) == t) & (TAGOF(a1) == t) & (TAGOF(a2) == t) &
                    (TAGOF(a3) == t);
            }
            if (lane < NV) {
              const u64 ah = ld_tag(&hpb[2 * lane]);
              hv = VALOF(ah);
              ok &= (TAGOF(ah) == t);
            }
          }
          if (__ballot(!ok) == 0ull) {
            cs = (c0 + c1) + (c2 + c3);
            hp = hv;
            break;
          }
          __builtin_amdgcn_s_sleep(1);
        }
        const float S = __shfl(cs, NV, 64);
        const float ov = cs * (1.0f / S) + hp;
        unsigned long long key = 0ull;
        if (lane < NV) {
          unsigned u_ = __float_as_uint(ov);
          u_ = (u_ & 0x80000000u) ? ~u_ : (u_ | 0x80000000u);
          key = ((unsigned long long)u_ << 32) | (unsigned)(~lane);
        }
#pragma unroll
        for (int m = 32; m > 0; m >>= 1) {
          const unsigned long long k2 = __shfl_xor(key, m, 64);
          if (k2 > key) key = k2;
        }
        const int best = (int)(~(unsigned)key);
        if (b == 0 && lane < NV) o[(size_t)(t - 1) * NV + lane] = ov;
        if (lane == 0) {
          sc_lds[0] = S;
          if (b == 0) {
            if (best == EOS_IDX && eos_reg < 0) eos_reg = t - 1;
            if (t == MAXLEN)
              o[(size_t)MAXLEN * NV] =
                  (eos_reg < 0) ? (float)MAXLEN : (float)eos_reg;
          }
          st_lds_rel(&bf_lds, (t << 6) | best);
        }
      }
    } else if (wave >= 8 && t < MAXLEN) {
      // ---- GRU waves: poll tagged gh directly (overlaps wave0 decide) ----
      const int j = tid - 512;
      float* ghbuf = ws + WS_GH + (size_t)((t + 1) & 1) * 3072;
      float ghr, ghz, ghn;
      for (;;) {
        const u64 a0 = ld_tag(&ghbuf[2 * j]);
        const u64 a1 = ld_tag(&ghbuf[2 * (j + 512)]);
        const u64 a2 = ld_tag(&ghbuf[2 * (j + 1024)]);
        if ((TAGOF(a0) == t + 1) && (TAGOF(a1) == t + 1) &&
            (TAGOF(a2) == t + 1)) {
          ghr = VALOF(a0); ghz = VALOF(a1); ghn = VALOF(a2);
          break;
        }
        __builtin_amdgcn_s_sleep(1);
      }
      int bf;
      while (((bf = ld_lds_acq(&bf_lds)) >> 6) < t) __builtin_amdgcn_s_sleep(1);
      const float* gi = ws + WS_GI + (size_t)(bf & 63) * 1536;
      const float gir = gi[j], giz = gi[j + 512], gin = gi[j + 1024];
      const float r_ = 1.0f / (1.0f + expf(-(gir + ghr)));
      const float z_ = 1.0f / (1.0f + expf(-(giz + ghz)));
      const float n_ = tanhf(gin + r_ * ghn);
      h_lds[j] = (1.0f - z_) * n_ + z_ * h_lds[j];
    }
    __syncthreads();  // barrier A: h_t, sc_lds ready

    // store previous step's normalized attention weights (p in regs)
    if (t > 0 && lane < RPW) {
      float pv = pz[0];
#pragma unroll
      for (int r = 1; r < RPW; ++r) pv = (lane == r) ? pz[r] : pv;
      attn[(size_t)(t - 1) * TENC + r0 + wave * RPW + lane] =
          pv * (1.0f / sc_lds[0]);
    }
    if (t == MAXLEN) break;

    // ---- dots: K in registers, h and aux rows in LDS ----
    {
      const float4 hh0 = ((const float4*)h_lds)[lane];
      const float4 hh1 = ((const float4*)h_lds)[lane + 64];
      float dsum[RPW];
#pragma unroll
      for (int r = 0; r < RPW; ++r) dsum[r] = dot8(ka[r], kb[r], hh0, hh1);
#pragma unroll
      for (int r = 0; r < RPW; ++r) dsum[r] = wred(dsum[r]);
      float fold = 0.f;
#pragma unroll
      for (int r = 0; r < RPW; ++r) {
        const float p = expf(dsum[r] * SCALE);
        pz[r] = p;
        fold += p * Mv[r];
      }
      if (lane < 41) pw_lds[wave * 48 + lane] = fold;
      if (wave >= 1 && wave <= 12) {  // gh rows for step t+1 -> tag t+2
        const int jr = (wave - 1) * 2;
        const float d0 =
            wred(dot8(((const float4*)(whh_lds + jr * 512))[lane],
                      ((const float4*)(whh_lds + jr * 512))[lane + 64], hh0,
                      hh1));
        const float d1 =
            wred(dot8(((const float4*)(whh_lds + (jr + 1) * 512))[lane],
                      ((const float4*)(whh_lds + (jr + 1) * 512))[lane + 64],
                      hh0, hh1));
        if (lane == 0) {
          float* g = ws + WS_GH + (size_t)(t & 1) * 3072;
          st_tag(&g[2 * (b * GHROWS + jr)], d0 + ghbias0, t + 2);
          st_tag(&g[2 * (b * GHROWS + jr + 1)], d1 + ghbias1, t + 2);
        }
      } else if (wave == 13 && b < NV) {  // hp row -> tag t+1
        const float d = wred(dot8(((const float4*)whp_lds)[lane],
                                  ((const float4*)whp_lds)[lane + 64], hh0,
                                  hh1));
        if (lane == 0)
          st_tag(&ws[WS_HP + (size_t)((t + 1) & 1) * RSTRIDE + 2 * b],
                 d + hpbias, t + 1);
      }
    }
    __syncthreads();  // barrier C: pw complete

    // ---- wave0: reduce 16 wave-partials, push tagged record ----
    if (wave == 0 && lane < 41) {
      float s = 0.f;
#pragma unroll
      for (int w2 = 0; w2 < NW; ++w2) s += pw_lds[w2 * 48 + lane];
      st_tag(&ws[WS_DEC + (size_t)((t + 1) & 1) * (NB * RSTRIDE) +
                 b * RSTRIDE + 2 * lane],
             s, t + 1);
    }
  }
}

extern "C" void kernel_launch(void* const* d_in, const int* in_sizes, int n_in,
                              void* d_out, int out_size, void* d_ws,
                              size_t ws_size, hipStream_t stream) {
  const float* enc    = (const float*)d_in[0];
  const float* hidden = (const float*)d_in[1];
  const float* embed  = (const float*)d_in[2];
  const float* w_ih   = (const float*)d_in[3];
  const float* w_hh   = (const float*)d_in[4];
  const float* b_ih   = (const float*)d_in[5];
  const float* b_hh   = (const float*)d_in[6];
  const float* w_out  = (const float*)d_in[7];
  const float* b_out  = (const float*)d_in[8];
  float* out = (float*)d_out;
  float* ws  = (float*)d_ws;

  dec_init<<<dim3(1), dim3(NT), 0, stream>>>((int*)d_ws);
  dec_main<<<dim3(NB), dim3(NT), 0, stream>>>(enc, hidden, embed, w_ih, w_hh,
                                              b_ih, b_hh, w_out, b_out, out,
                                              ws);
}